// Round 7
// baseline (58.550 us; speedup 1.0000x reference)
//
#include <hip/hip_runtime.h>

// Problem constants (fixed by reference): B=8, H=32, S=64, C=4096, D=128
#define BB 8
#define HH 32
#define SS 64
#define CC 4096
#define DD 128
#define MAXU 2176   // per-batch compacted stride (used <= 2112, occ == 2112)

// ---------------------------------------------------------------------------
// ws layout (units: 4-byte words) — every buffer write-before-read, no memset.
//   rowptr   : 32832   (B*4104 CSR edge row pointers; [4096]=total)
//   adj      : 16384   (B*2048 dest cols, CSR order)
//   s        : 32768   (B*C f32 sqrt(1+indeg))
//   te       : 16384   (S*256 f32 temporal table)
//   inv      : 17408   (B*MAXU slot -> candidate)
//   nused    : 64      (B u32)
//   occp     : 32832   (B*4104 occurrence CSR ptrs per candidate)
//   occ_list : 17408   (B*MAXU entries (outrow<<6|s))
//   Wt       : 16384   (W transposed, Wt[k*128+n] = W[n*128+k])
// ---------------------------------------------------------------------------

// Blocks 0..7: per-batch graph build (edge dedupe + CSR + used-compaction +
// occurrence CSR). Blocks 8..23: te table. Blocks 24..39: W transpose.
__global__ __launch_bounds__(1024) void build_graph(const int* __restrict__ hist,
                                                    const int* __restrict__ cur,
                                                    const float* __restrict__ W,
                                                    unsigned* __restrict__ rowptr,
                                                    unsigned* __restrict__ adj,
                                                    float* __restrict__ s,
                                                    unsigned* __restrict__ inv,
                                                    unsigned* __restrict__ nused,
                                                    unsigned* __restrict__ occp,
                                                    unsigned* __restrict__ occ_list,
                                                    float* __restrict__ te,
                                                    float* __restrict__ Wt) {
    const int tid = threadIdx.x;
    if (blockIdx.x >= BB + 16) {                   // W transpose: 16 blocks
        int g = (blockIdx.x - BB - 16) * 1024 + tid;   // 16384 elems
        int k = g >> 7, n = g & 127;
        Wt[g] = W[n * 128 + k];
        return;
    }
    if (blockIdx.x >= BB) {                        // te table: 16 blocks
        int g = (blockIdx.x - BB) * 1024 + tid;    // S*256 = 16384
        int t = g >> 8, c = g & 255, k = c >> 1;
        float ang = (float)t * powf(10000.0f, -(float)k / 128.0f);
        te[g] = (c & 1) ? cosf(ang) : sinf(ang);
        return;
    }
    __shared__ unsigned table[4096];    // hash set of edge keys
    __shared__ unsigned cnt_a[4096];    // in-degree; later scatter cursors
    __shared__ unsigned cnt_b[4096];    // out-degree; later occurrence counts
    __shared__ unsigned used[4096];
    __shared__ unsigned pref[4096];
    __shared__ unsigned lkeys[2048];
    __shared__ unsigned wbase[17];
    __shared__ unsigned total;
    const int b = blockIdx.x;
    const int lane = tid & 63, wv = tid >> 6;

#pragma unroll
    for (int r = 0; r < 4; ++r) {
        int g = tid + r * 1024;
        table[g] = 0xFFFFFFFFu;
        cnt_a[g] = 0u;
        cnt_b[g] = 0u;
        used[g] = 0u;
    }
    if (tid == 0) total = 0u;
    __syncthreads();

    for (int t = tid; t < HH * SS; t += 1024) used[hist[b * HH * SS + t]] = 1u;
    if (tid < SS) used[cur[b * SS + tid]] = 1u;

    for (int t = tid; t < HH * (SS - 1); t += 1024) {   // edge dedupe
        int h = t / 63, ss = t - h * 63;
        int base = (b * HH + h) * SS + ss;
        int i = hist[base], j = hist[base + 1];
        if (i != j) {
            unsigned key = ((unsigned)i << 12) | (unsigned)j;
            unsigned hh = (key * 2654435761u) >> 20;
            for (;;) {
                hh &= 4095u;
                unsigned old = atomicCAS(&table[hh], 0xFFFFFFFFu, key);
                if (old == 0xFFFFFFFFu) {
                    unsigned slot = atomicAdd(&total, 1u);
                    lkeys[slot] = key;
                    atomicAdd(&cnt_a[key & 4095u], 1u);
                    atomicAdd(&cnt_b[key >> 12], 1u);
                    break;
                }
                if (old == key) break;
                ++hh;
            }
        }
    }
    __syncthreads();

#pragma unroll
    for (int r = 0; r < 4; ++r) {                  // s from in-degree
        int g = tid + r * 1024;
        s[b * CC + g] = sqrtf(1.0f + (float)cnt_a[g]);
    }

    // ---- scan #1 (packed): v = (outdeg<<13)|used -> CSR rowptr + slot map
    {
        unsigned v0 = (cnt_b[tid * 4]     << 13) | used[tid * 4];
        unsigned v1 = (cnt_b[tid * 4 + 1] << 13) | used[tid * 4 + 1];
        unsigned v2 = (cnt_b[tid * 4 + 2] << 13) | used[tid * 4 + 2];
        unsigned v3 = (cnt_b[tid * 4 + 3] << 13) | used[tid * 4 + 3];
        unsigned tsum = v0 + v1 + v2 + v3;
        unsigned x = tsum;
#pragma unroll
        for (int off = 1; off < 64; off <<= 1) {
            unsigned y = __shfl_up(x, off);
            if (lane >= off) x += y;
        }
        if (lane == 63) wbase[wv + 1] = x;
        __syncthreads();
        if (tid == 0) {
            wbase[0] = 0u;
            for (int w = 1; w <= 16; ++w) wbase[w] += wbase[w - 1];
        }
        __syncthreads();
        unsigned texcl = wbase[wv] + x - tsum;
        pref[tid * 4]     = texcl;
        pref[tid * 4 + 1] = texcl + v0;
        pref[tid * 4 + 2] = texcl + v0 + v1;
        pref[tid * 4 + 3] = texcl + v0 + v1 + v2;
    }
#pragma unroll
    for (int r = 0; r < 4; ++r) cnt_a[tid + r * 1024] = 0u;   // scatter cursors
    __syncthreads();

#pragma unroll
    for (int r = 0; r < 4; ++r) {
        int g = tid + r * 1024;
        unsigned p = pref[g];
        rowptr[b * 4104 + g] = p >> 13;
        if (used[g]) inv[b * MAXU + (p & 8191u)] = (unsigned)g;
    }
    if (tid == 0) {
        rowptr[b * 4104 + 4096] = wbase[16] >> 13;
        nused[b] = wbase[16] & 8191u;
    }
    for (int e = tid; e < (int)total; e += 1024) { // adjacency scatter
        unsigned key = lkeys[e];
        unsigned i = key >> 12, j = key & 4095u;
        unsigned pos = (pref[i] >> 13) + atomicAdd(&cnt_a[i], 1u);
        adj[b * 2048 + pos] = j;
    }
    __syncthreads();

    // ---- occurrence counting
#pragma unroll
    for (int r = 0; r < 4; ++r) cnt_b[tid + r * 1024] = 0u;
    __syncthreads();
    for (int t = tid; t < HH * SS; t += 1024) atomicAdd(&cnt_b[hist[b * HH * SS + t]], 1u);
    if (tid < SS) atomicAdd(&cnt_b[cur[b * SS + tid]], 1u);
    __syncthreads();

    // ---- scan #2 (plain) over occurrence counts -> occp
    {
        unsigned v0 = cnt_b[tid * 4], v1 = cnt_b[tid * 4 + 1];
        unsigned v2 = cnt_b[tid * 4 + 2], v3 = cnt_b[tid * 4 + 3];
        unsigned tsum = v0 + v1 + v2 + v3;
        unsigned x = tsum;
#pragma unroll
        for (int off = 1; off < 64; off <<= 1) {
            unsigned y = __shfl_up(x, off);
            if (lane >= off) x += y;
        }
        if (lane == 63) wbase[wv + 1] = x;
        __syncthreads();
        if (tid == 0) {
            wbase[0] = 0u;
            for (int w = 1; w <= 16; ++w) wbase[w] += wbase[w - 1];
        }
        __syncthreads();
        unsigned texcl = wbase[wv] + x - tsum;
        pref[tid * 4]     = texcl;
        pref[tid * 4 + 1] = texcl + v0;
        pref[tid * 4 + 2] = texcl + v0 + v1;
        pref[tid * 4 + 3] = texcl + v0 + v1 + v2;
    }
#pragma unroll
    for (int r = 0; r < 4; ++r) cnt_a[tid + r * 1024] = 0u;   // occ cursors
    __syncthreads();

#pragma unroll
    for (int r = 0; r < 4; ++r) {
        int g = tid + r * 1024;
        occp[b * 4104 + g] = pref[g];
    }
    if (tid == 0) occp[b * 4104 + 4096] = wbase[16];

    for (int t = tid; t < HH * SS; t += 1024) {    // hist occurrences
        int cand = hist[b * HH * SS + t];
        unsigned pos = pref[cand] + atomicAdd(&cnt_a[cand], 1u);
        occ_list[b * MAXU + pos] = ((unsigned)(b * 2048 + t) << 6) | (unsigned)(t & 63);
    }
    if (tid < SS) {                                // cur occurrences
        int cand = cur[b * SS + tid];
        unsigned pos = pref[cand] + atomicAdd(&cnt_a[cand], 1u);
        occ_list[b * MAXU + pos] =
            ((unsigned)(BB * HH * SS + b * SS + tid) << 6) | (unsigned)tid;
    }
}

// Fused tail, occupancy-first rewrite (R6: 73KB LDS -> 2 blk/CU, 13% occ,
// 1.76M bank conflicts). LDS ~17KB; W read direct from global (L1/L2-hot,
// broadcast); As stride 131 => conflict-free GEMM reads; split-halves
// (lane / 64+lane) phase-1 => 2-way (free); parallel edge->row via ballot.
__global__ __launch_bounds__(256, 4) void fused_tail(const float* __restrict__ E,
                                                  const float* __restrict__ s,
                                                  const unsigned* __restrict__ rowptr,
                                                  const unsigned* __restrict__ adj,
                                                  const unsigned* __restrict__ inv,
                                                  const unsigned* __restrict__ nused,
                                                  const float* __restrict__ Wt,
                                                  const float* __restrict__ bg,
                                                  const unsigned* __restrict__ occp,
                                                  const unsigned* __restrict__ occ_list,
                                                  const float* __restrict__ te,
                                                  float* __restrict__ out) {
    __shared__ float As[32][131];     // ae rows, then eg rows; odd stride
    __shared__ unsigned c_l[32];
    __shared__ float si_l[32];
    __shared__ unsigned estart[32];
    __shared__ unsigned ebounds[2];
    const int b = blockIdx.x / 66;
    const int s0 = (blockIdx.x % 66) * 32;
    const unsigned nu = nused[b];
    if ((unsigned)s0 >= nu) return;
    const int tid = threadIdx.x;
    const int lane = tid & 63, wv = tid >> 6;

    if (tid < 32) {
        unsigned slot = (unsigned)(s0 + tid);
        unsigned c = 0xFFFFFFFFu; float si = 0.f; unsigned es = 0xFFFFFFFFu;
        if (slot < nu) {
            c = inv[b * MAXU + slot];
            si = s[b * CC + c];
            es = rowptr[b * 4104 + c];
        }
        c_l[tid] = c; si_l[tid] = si; estart[tid] = es;
    }
    __syncthreads();
    if (tid == 0) {
        unsigned nv = nu - (unsigned)s0; if (nv > 32u) nv = 32u;
        ebounds[0] = estart[0];
        ebounds[1] = rowptr[b * 4104 + c_l[nv - 1] + 1];
    }

    // phase 1a: As[r] = si * E[c] (zeros for invalid tail rows)
    const float* Ebase = E + (size_t)b * CC * DD;
#pragma unroll
    for (int q = 0; q < 8; ++q) {
        int r = wv * 8 + q;
        unsigned c = c_l[r];
        float e0 = 0.f, e1 = 0.f;
        if (c != 0xFFFFFFFFu) {
            e0 = Ebase[(size_t)c * DD + lane];
            e1 = Ebase[(size_t)c * DD + 64 + lane];
        }
        float si = si_l[r];
        As[r][lane]      = si * e0;       // 2-way banks: free
        As[r][64 + lane] = si * e1;
    }
    __syncthreads();                       // As init done; ebounds visible

    // phase 1b: edge-parallel accumulate (wave per edge); row via ballot+clz
    {
        unsigned myes = (lane < 32) ? estart[lane] : 0xFFFFFFFFu;
        unsigned e_beg = ebounds[0], e_end = ebounds[1];
        for (unsigned pe = e_beg + (unsigned)wv; pe < e_end; pe += 4) {
            unsigned long long bal = __ballot(myes <= pe);
            int r = 63 - __builtin_clzll(bal);
            unsigned j = adj[b * 2048 + pe];
            float sj = s[b * CC + j];
            float ej0 = Ebase[(size_t)j * DD + lane];
            float ej1 = Ebase[(size_t)j * DD + 64 + lane];
            atomicAdd(&As[r][lane],      sj * ej0);
            atomicAdd(&As[r][64 + lane], sj * ej1);
        }
    }
    __syncthreads();

    // phase 1c: final scale by s_i
#pragma unroll
    for (int q = 0; q < 8; ++q) {
        int r = wv * 8 + q;
        float si = si_l[r];
        As[r][lane]      *= si;
        As[r][64 + lane] *= si;
    }
    __syncthreads();

    // phase 2: eg = relu(ae @ W^T + bias); W read direct from global Wt
    const int tr = tid >> 4, tc = tid & 15;
    float bgv[8];
#pragma unroll
    for (int c = 0; c < 8; ++c) bgv[c] = bg[tc * 8 + c];
    float acc[2][8];
#pragma unroll
    for (int r = 0; r < 2; ++r)
#pragma unroll
        for (int c = 0; c < 8; ++c) acc[r][c] = 0.f;

#pragma unroll 4
    for (int k = 0; k < 128; ++k) {
        float a0 = As[tr * 2][k];          // 16 distinct banks: conflict-free
        float a1 = As[tr * 2 + 1][k];
        const float4* wp = (const float4*)(Wt + k * 128 + tc * 8);
        float4 w0 = wp[0], w1 = wp[1];     // broadcast across 16 thr, L1/L2-hot
        float wvv[8] = {w0.x, w0.y, w0.z, w0.w, w1.x, w1.y, w1.z, w1.w};
#pragma unroll
        for (int c = 0; c < 8; ++c) {
            acc[0][c] = fmaf(a0, wvv[c], acc[0][c]);
            acc[1][c] = fmaf(a1, wvv[c], acc[1][c]);
        }
    }
    __syncthreads();                       // all GEMM As reads complete
#pragma unroll
    for (int r = 0; r < 2; ++r) {
        int row = tr * 2 + r;
#pragma unroll
        for (int c = 0; c < 8; ++c)
            As[row][tc * 8 + c] = fmaxf(acc[r][c] + bgv[c], 0.f);
    }
    __syncthreads();

    // phase 3: occurrence writes  out[row] = [eg | E] + te[s]
    const float4* te4 = (const float4*)te;
    const float4* E4 = (const float4*)E;
    float4* out4 = (float4*)out;
#pragma unroll
    for (int q = 0; q < 8; ++q) {
        int r = wv * 8 + q;
        unsigned c = c_l[r];
        if (c == 0xFFFFFFFFu) continue;
        float4 v;
        if (lane < 32) {
            v.x = As[r][lane * 4];
            v.y = As[r][lane * 4 + 1];
            v.z = As[r][lane * 4 + 2];
            v.w = As[r][lane * 4 + 3];
        } else {
            v = E4[(size_t)(b * CC + c) * 32 + (lane - 32)];
        }
        unsigned o0 = occp[b * 4104 + c], o1 = occp[b * 4104 + c + 1];
        for (unsigned o = o0; o < o1; ++o) {
            unsigned ent = occ_list[b * MAXU + o];
            unsigned outrow = ent >> 6, spos = ent & 63u;
            float4 t = te4[spos * 64 + lane];
            out4[(size_t)outrow * 64 + lane] =
                make_float4(v.x + t.x, v.y + t.y, v.z + t.z, v.w + t.w);
        }
    }
}

extern "C" void kernel_launch(void* const* d_in, const int* in_sizes, int n_in,
                              void* d_out, int out_size, void* d_ws, size_t ws_size,
                              hipStream_t stream) {
    const int*   hist = (const int*)d_in[1];
    const int*   cur  = (const int*)d_in[2];
    const float* E    = (const float*)d_in[3];
    const float* W    = (const float*)d_in[4];
    const float* bg   = (const float*)d_in[5];
    float* out = (float*)d_out;

    unsigned* ws_u     = (unsigned*)d_ws;
    unsigned* rowptr   = ws_u;                       // 32832
    unsigned* adj      = rowptr + 32832;             // 16384
    float*    sarr     = (float*)(adj + 16384);      // 32768
    float*    te       = sarr + 32768;               // 16384
    unsigned* inv      = (unsigned*)(te + 16384);    // 17408
    unsigned* nused    = inv + 17408;                // 64
    unsigned* occp     = nused + 64;                 // 32832
    unsigned* occ_list = occp + 32832;               // 17408
    float*    Wt       = (float*)(occ_list + 17408); // 16384

    build_graph<<<BB + 32, 1024, 0, stream>>>(hist, cur, W, rowptr, adj, sarr,
                                              inv, nused, occp, occ_list, te, Wt);
    fused_tail<<<BB * 66, 256, 0, stream>>>(E, sarr, rowptr, adj, inv, nused,
                                            Wt, bg, occp, occ_list, te, out);
}

// Round 8
// 51.633 us; speedup vs baseline: 1.1340x; 1.1340x over previous
//
#include <hip/hip_runtime.h>

// Problem constants (fixed by reference): B=8, H=32, S=64, C=4096, D=128
#define BB 8
#define HH 32
#define SS 64
#define CC 4096
#define DD 128
#define MAXU 2176   // per-batch compacted slot stride (used <= 2112)

// ---------------------------------------------------------------------------
// ws layout (units: 4-byte words) — every buffer write-before-read, no memset.
//   rowptr : 32832    (B*4104 CSR edge row pointers; [4096]=total)
//   adj    : 16384    (B*2048 dest cols, CSR order)
//   s      : 32768    (B*C f32 sqrt(1+indeg))
//   te     : 16384    (S*256 f32 temporal table)
//   inv    : 17408    (B*MAXU slot -> candidate)
//   remap  : 32768    (B*C cand -> slot, valid where used)
//   nused  : 64       (B u32)
//   Wt     : 16384    (W transposed, Wt[k*128+n] = W[n*128+k])
//   ae_c   : 2228224  (B*MAXU*D f32 compact normalized A@E rows)
//   eg_c   : 2228224  (B*MAXU*D f32 compact relu(ae@W^T+b))
// ---------------------------------------------------------------------------

// Blocks 0..7: per-batch graph build (edge dedupe + CSR + used-compaction).
// Blocks 8..23: te table. Blocks 24..39: W transpose.
__global__ __launch_bounds__(1024) void build_graph(const int* __restrict__ hist,
                                                    const int* __restrict__ cur,
                                                    const float* __restrict__ W,
                                                    unsigned* __restrict__ rowptr,
                                                    unsigned* __restrict__ adj,
                                                    float* __restrict__ s,
                                                    unsigned* __restrict__ inv,
                                                    unsigned* __restrict__ remap,
                                                    unsigned* __restrict__ nused,
                                                    float* __restrict__ te,
                                                    float* __restrict__ Wt) {
    const int tid = threadIdx.x;
    if (blockIdx.x >= BB + 16) {                   // W transpose: 16 blocks
        int g = (blockIdx.x - BB - 16) * 1024 + tid;   // 16384 elems
        int k = g >> 7, n = g & 127;
        Wt[g] = W[n * 128 + k];
        return;
    }
    if (blockIdx.x >= BB) {                        // te table: 16 blocks
        int g = (blockIdx.x - BB) * 1024 + tid;    // S*256 = 16384
        int t = g >> 8, c = g & 255, k = c >> 1;
        float ang = (float)t * powf(10000.0f, -(float)k / 128.0f);
        te[g] = (c & 1) ? cosf(ang) : sinf(ang);
        return;
    }
    __shared__ unsigned table[4096];    // hash set of edge keys
    __shared__ unsigned cnt_a[4096];    // in-degree; later scatter cursors
    __shared__ unsigned cnt_b[4096];    // out-degree
    __shared__ unsigned used[4096];
    __shared__ unsigned pref[4096];
    __shared__ unsigned lkeys[2048];
    __shared__ unsigned wbase[17];
    __shared__ unsigned total;
    const int b = blockIdx.x;
    const int lane = tid & 63, wv = tid >> 6;

#pragma unroll
    for (int r = 0; r < 4; ++r) {
        int g = tid + r * 1024;
        table[g] = 0xFFFFFFFFu;
        cnt_a[g] = 0u;
        cnt_b[g] = 0u;
        used[g] = 0u;
    }
    if (tid == 0) total = 0u;
    __syncthreads();

    for (int t = tid; t < HH * SS; t += 1024) used[hist[b * HH * SS + t]] = 1u;
    if (tid < SS) used[cur[b * SS + tid]] = 1u;

    for (int t = tid; t < HH * (SS - 1); t += 1024) {   // edge dedupe
        int h = t / 63, ss = t - h * 63;
        int base = (b * HH + h) * SS + ss;
        int i = hist[base], j = hist[base + 1];
        if (i != j) {
            unsigned key = ((unsigned)i << 12) | (unsigned)j;
            unsigned hh = (key * 2654435761u) >> 20;
            for (;;) {
                hh &= 4095u;
                unsigned old = atomicCAS(&table[hh], 0xFFFFFFFFu, key);
                if (old == 0xFFFFFFFFu) {
                    unsigned slot = atomicAdd(&total, 1u);
                    lkeys[slot] = key;
                    atomicAdd(&cnt_a[key & 4095u], 1u);
                    atomicAdd(&cnt_b[key >> 12], 1u);
                    break;
                }
                if (old == key) break;
                ++hh;
            }
        }
    }
    __syncthreads();

#pragma unroll
    for (int r = 0; r < 4; ++r) {                  // s from in-degree
        int g = tid + r * 1024;
        s[b * CC + g] = sqrtf(1.0f + (float)cnt_a[g]);
    }

    // packed scan: v = (outdeg<<13)|used -> CSR rowptr + compact slot map
    {
        unsigned v0 = (cnt_b[tid * 4]     << 13) | used[tid * 4];
        unsigned v1 = (cnt_b[tid * 4 + 1] << 13) | used[tid * 4 + 1];
        unsigned v2 = (cnt_b[tid * 4 + 2] << 13) | used[tid * 4 + 2];
        unsigned v3 = (cnt_b[tid * 4 + 3] << 13) | used[tid * 4 + 3];
        unsigned tsum = v0 + v1 + v2 + v3;
        unsigned x = tsum;
#pragma unroll
        for (int off = 1; off < 64; off <<= 1) {
            unsigned y = __shfl_up(x, off);
            if (lane >= off) x += y;
        }
        if (lane == 63) wbase[wv + 1] = x;
        __syncthreads();
        if (tid == 0) {
            wbase[0] = 0u;
            for (int w = 1; w <= 16; ++w) wbase[w] += wbase[w - 1];
        }
        __syncthreads();
        unsigned texcl = wbase[wv] + x - tsum;
        pref[tid * 4]     = texcl;
        pref[tid * 4 + 1] = texcl + v0;
        pref[tid * 4 + 2] = texcl + v0 + v1;
        pref[tid * 4 + 3] = texcl + v0 + v1 + v2;
    }
#pragma unroll
    for (int r = 0; r < 4; ++r) cnt_a[tid + r * 1024] = 0u;   // scatter cursors
    __syncthreads();

#pragma unroll
    for (int r = 0; r < 4; ++r) {
        int g = tid + r * 1024;
        unsigned p = pref[g];
        rowptr[b * 4104 + g] = p >> 13;
        unsigned slot = p & 8191u;
        remap[b * CC + g] = slot;
        if (used[g]) inv[b * MAXU + slot] = (unsigned)g;
    }
    if (tid == 0) {
        rowptr[b * 4104 + 4096] = wbase[16] >> 13;
        nused[b] = wbase[16] & 8191u;
    }
    for (int e = tid; e < (int)total; e += 1024) { // adjacency scatter
        unsigned key = lkeys[e];
        unsigned i = key >> 12, j = key & 4095u;
        unsigned pos = (pref[i] >> 13) + atomicAdd(&cnt_a[i], 1u);
        adj[b * 2048 + pos] = j;
    }
}

// One WAVE per used row: ae = s_i*(s_i*E[i] + sum_{i->j} s_j*E[j]) -> ae_c.
// No LDS, no barriers; 4352 blocks give the TLP to hide the edge chains.
__global__ __launch_bounds__(256) void ae_build(const float* __restrict__ E,
                                                const float* __restrict__ s,
                                                const unsigned* __restrict__ rowptr,
                                                const unsigned* __restrict__ adj,
                                                const unsigned* __restrict__ inv,
                                                const unsigned* __restrict__ nused,
                                                float* __restrict__ ae_c) {
    const int b = blockIdx.x / (MAXU / 4);                 // 544 blocks per batch
    const int slot = (blockIdx.x % (MAXU / 4)) * 4 + (threadIdx.x >> 6);
    const int lane = threadIdx.x & 63;
    if ((unsigned)slot >= nused[b]) return;
    unsigned c = inv[b * MAXU + slot];
    float si = s[b * CC + c];
    const float2* Eb = (const float2*)(E + (size_t)b * CC * DD);
    float2 e = Eb[(size_t)c * 64 + lane];
    float2 acc = make_float2(si * e.x, si * e.y);
    unsigned p0 = rowptr[b * 4104 + c], p1 = rowptr[b * 4104 + c + 1];
    for (unsigned p = p0; p < p1; ++p) {
        unsigned j = adj[b * 2048 + p];
        float sj = s[b * CC + j];
        float2 ej = Eb[(size_t)j * 64 + lane];
        acc.x += sj * ej.x;
        acc.y += sj * ej.y;
    }
    ((float2*)ae_c)[((size_t)b * MAXU + slot) * 64 + lane] =
        make_float2(si * acc.x, si * acc.y);
}

// Compact dense GEMM: eg_c = relu(ae_c @ W^T + bias). 32 rows/block, 544
// blocks (~2/CU, 2 waves/SIMD). As stride 131: GEMM reads hit 16 distinct
// banks (6*tr+k mod 32 all-distinct). W broadcast-read from global (L1-hot).
__global__ __launch_bounds__(256) void gemm_eg(const float* __restrict__ ae_c,
                                               const float* __restrict__ Wt,
                                               const float* __restrict__ bg,
                                               const unsigned* __restrict__ nused,
                                               float* __restrict__ eg_c) {
    __shared__ float As[32][131];
    const int b = blockIdx.x / (MAXU / 32);                // 68 blocks per batch
    const int s0 = (blockIdx.x % (MAXU / 32)) * 32;
    const unsigned nu = nused[b];
    if ((unsigned)s0 >= nu) return;
    const int tid = threadIdx.x;

    // stage 32 ae rows (poison rows beyond nu are harmless f32 garbage)
    for (int idx = tid; idx < 1024; idx += 256) {
        int row = idx >> 5, f4 = idx & 31;
        float4 v = ((const float4*)ae_c)[((size_t)b * MAXU + s0 + row) * 32 + f4];
        As[row][f4 * 4]     = v.x;
        As[row][f4 * 4 + 1] = v.y;
        As[row][f4 * 4 + 2] = v.z;
        As[row][f4 * 4 + 3] = v.w;
    }
    __syncthreads();

    const int tr = tid >> 4, tc = tid & 15;
    float bgv[8];
#pragma unroll
    for (int c = 0; c < 8; ++c) bgv[c] = bg[tc * 8 + c];
    float acc[2][8];
#pragma unroll
    for (int r = 0; r < 2; ++r)
#pragma unroll
        for (int c = 0; c < 8; ++c) acc[r][c] = 0.f;

#pragma unroll 4
    for (int k = 0; k < 128; ++k) {
        float a0 = As[tr * 2][k];
        float a1 = As[tr * 2 + 1][k];
        const float4* wp = (const float4*)(Wt + k * 128 + tc * 8);
        float4 w0 = wp[0], w1 = wp[1];
        float wvv[8] = {w0.x, w0.y, w0.z, w0.w, w1.x, w1.y, w1.z, w1.w};
#pragma unroll
        for (int c = 0; c < 8; ++c) {
            acc[0][c] = fmaf(a0, wvv[c], acc[0][c]);
            acc[1][c] = fmaf(a1, wvv[c], acc[1][c]);
        }
    }

#pragma unroll
    for (int r = 0; r < 2; ++r) {
        int row = tr * 2 + r;
        float4 o0, o1;
        o0.x = fmaxf(acc[r][0] + bgv[0], 0.f);
        o0.y = fmaxf(acc[r][1] + bgv[1], 0.f);
        o0.z = fmaxf(acc[r][2] + bgv[2], 0.f);
        o0.w = fmaxf(acc[r][3] + bgv[3], 0.f);
        o1.x = fmaxf(acc[r][4] + bgv[4], 0.f);
        o1.y = fmaxf(acc[r][5] + bgv[5], 0.f);
        o1.z = fmaxf(acc[r][6] + bgv[6], 0.f);
        o1.w = fmaxf(acc[r][7] + bgv[7], 0.f);
        float* outp = eg_c + ((size_t)b * MAXU + s0 + row) * 128 + tc * 8;
        ((float4*)outp)[0] = o0;
        ((float4*)outp)[1] = o1;
    }
}

// One wave per output row: out[row] = [eg_c[remap[cand]] | E[cand]] + te[s].
__global__ __launch_bounds__(256) void scatter_out(const int* __restrict__ hist,
                                                   const int* __restrict__ cur,
                                                   const unsigned* __restrict__ remap,
                                                   const float4* __restrict__ Egc4,
                                                   const float4* __restrict__ E4,
                                                   const float4* __restrict__ te4,
                                                   float4* __restrict__ out4) {
    int g = blockIdx.x * 256 + threadIdx.x;
    int row = g >> 6, lane = g & 63;
    int b, spos, cand;
    if (row < BB * HH * SS) {
        spos = row & 63;
        b = row >> 11;
        cand = hist[row];
    } else {
        int rc = row - BB * HH * SS;
        spos = rc & 63;
        b = rc >> 6;
        cand = cur[rc];
    }
    float4 v;
    if (lane < 32) {
        unsigned slot = remap[b * CC + cand];
        v = Egc4[((size_t)b * MAXU + slot) * 32 + lane];
    } else {
        v = E4[(size_t)(b * CC + cand) * 32 + (lane - 32)];
    }
    float4 t = te4[spos * 64 + lane];
    out4[(size_t)row * 64 + lane] = make_float4(v.x + t.x, v.y + t.y, v.z + t.z, v.w + t.w);
}

extern "C" void kernel_launch(void* const* d_in, const int* in_sizes, int n_in,
                              void* d_out, int out_size, void* d_ws, size_t ws_size,
                              hipStream_t stream) {
    const int*   hist = (const int*)d_in[1];
    const int*   cur  = (const int*)d_in[2];
    const float* E    = (const float*)d_in[3];
    const float* W    = (const float*)d_in[4];
    const float* bg   = (const float*)d_in[5];
    float* out = (float*)d_out;

    unsigned* ws_u   = (unsigned*)d_ws;
    unsigned* rowptr = ws_u;                         // 32832
    unsigned* adj    = rowptr + 32832;               // 16384
    float*    sarr   = (float*)(adj + 16384);        // 32768
    float*    te     = sarr + 32768;                 // 16384
    unsigned* inv    = (unsigned*)(te + 16384);      // 17408
    unsigned* remap  = inv + 17408;                  // 32768
    unsigned* nused  = remap + 32768;                // 64
    float*    Wt     = (float*)(nused + 64);         // 16384
    float*    ae_c   = Wt + 16384;                   // 2228224
    float*    eg_c   = ae_c + 2228224;               // 2228224

    build_graph<<<BB + 32, 1024, 0, stream>>>(hist, cur, W, rowptr, adj, sarr,
                                              inv, remap, nused, te, Wt);
    ae_build<<<BB * (MAXU / 4), 256, 0, stream>>>(E, sarr, rowptr, adj, inv,
                                                  nused, ae_c);
    gemm_eg<<<BB * (MAXU / 32), 256, 0, stream>>>(ae_c, Wt, bg, nused, eg_c);
    scatter_out<<<(BB * HH * SS + BB * SS) / 4, 256, 0, stream>>>(
        hist, cur, remap, (const float4*)eg_c, (const float4*)E,
        (const float4*)te, (float4*)out);
}

// Round 9
// 47.902 us; speedup vs baseline: 1.2223x; 1.0779x over previous
//
#include <hip/hip_runtime.h>

// Problem constants (fixed by reference): B=8, H=32, S=64, C=4096, D=128
#define BB 8
#define HH 32
#define SS 64
#define CC 4096
#define DD 128
#define MAXU 2176   // per-batch compacted slot stride (used <= 2112)

// ---------------------------------------------------------------------------
// ws layout (units: 4-byte words) — every buffer write-before-read, no memset.
//   rowptr : 32832    (B*4104 CSR edge row pointers; [4096]=total)
//   adj    : 16384    (B*2048 dest cols, CSR order)
//   s      : 32768    (B*C f32 sqrt(1+indeg))
//   te     : 16384    (S*256 f32 temporal table)
//   inv    : 17408    (B*MAXU slot -> candidate)
//   remap  : 32768    (B*C cand -> slot, valid where used)
//   nused  : 64       (B u32)
//   Wt     : 16384    (W transposed, Wt[k*128+n] = W[n*128+k])
//   ae_c   : 2228224  (B*MAXU*D f32 compact normalized A@E rows)
//   eg_c   : 2228224  (B*MAXU*D f32 compact relu(ae@W^T+b))
// ---------------------------------------------------------------------------

// Blocks 0..7: per-batch graph build (edge dedupe + CSR + used-compaction).
// Blocks 8..23: te table. Blocks 24..39: W transpose.
__global__ __launch_bounds__(1024) void build_graph(const int* __restrict__ hist,
                                                    const int* __restrict__ cur,
                                                    const float* __restrict__ W,
                                                    unsigned* __restrict__ rowptr,
                                                    unsigned* __restrict__ adj,
                                                    float* __restrict__ s,
                                                    unsigned* __restrict__ inv,
                                                    unsigned* __restrict__ remap,
                                                    unsigned* __restrict__ nused,
                                                    float* __restrict__ te,
                                                    float* __restrict__ Wt) {
    const int tid = threadIdx.x;
    if (blockIdx.x >= BB + 16) {                   // W transpose: 16 blocks
        int g = (blockIdx.x - BB - 16) * 1024 + tid;   // 16384 elems
        int k = g >> 7, n = g & 127;
        Wt[g] = W[n * 128 + k];
        return;
    }
    if (blockIdx.x >= BB) {                        // te table: 16 blocks
        int g = (blockIdx.x - BB) * 1024 + tid;    // S*256 = 16384
        int t = g >> 8, c = g & 255, k = c >> 1;
        float ang = (float)t * powf(10000.0f, -(float)k / 128.0f);
        te[g] = (c & 1) ? cosf(ang) : sinf(ang);
        return;
    }
    __shared__ unsigned table[4096];    // hash set of edge keys
    __shared__ unsigned cnt_a[4096];    // in-degree; later scatter cursors
    __shared__ unsigned cnt_b[4096];    // out-degree
    __shared__ unsigned used[4096];
    __shared__ unsigned pref[4096];
    __shared__ unsigned lkeys[2048];
    __shared__ unsigned wbase[17];
    __shared__ unsigned total;
    const int b = blockIdx.x;
    const int lane = tid & 63, wv = tid >> 6;

#pragma unroll
    for (int r = 0; r < 4; ++r) {
        int g = tid + r * 1024;
        table[g] = 0xFFFFFFFFu;
        cnt_a[g] = 0u;
        cnt_b[g] = 0u;
        used[g] = 0u;
    }
    if (tid == 0) total = 0u;
    __syncthreads();

    for (int t = tid; t < HH * SS; t += 1024) used[hist[b * HH * SS + t]] = 1u;
    if (tid < SS) used[cur[b * SS + tid]] = 1u;

    for (int t = tid; t < HH * (SS - 1); t += 1024) {   // edge dedupe
        int h = t / 63, ss = t - h * 63;
        int base = (b * HH + h) * SS + ss;
        int i = hist[base], j = hist[base + 1];
        if (i != j) {
            unsigned key = ((unsigned)i << 12) | (unsigned)j;
            unsigned hh = (key * 2654435761u) >> 20;
            for (;;) {
                hh &= 4095u;
                unsigned old = atomicCAS(&table[hh], 0xFFFFFFFFu, key);
                if (old == 0xFFFFFFFFu) {
                    unsigned slot = atomicAdd(&total, 1u);
                    lkeys[slot] = key;
                    atomicAdd(&cnt_a[key & 4095u], 1u);
                    atomicAdd(&cnt_b[key >> 12], 1u);
                    break;
                }
                if (old == key) break;
                ++hh;
            }
        }
    }
    __syncthreads();

#pragma unroll
    for (int r = 0; r < 4; ++r) {                  // s from in-degree
        int g = tid + r * 1024;
        s[b * CC + g] = sqrtf(1.0f + (float)cnt_a[g]);
    }

    // packed scan: v = (outdeg<<13)|used -> CSR rowptr + compact slot map
    {
        unsigned v0 = (cnt_b[tid * 4]     << 13) | used[tid * 4];
        unsigned v1 = (cnt_b[tid * 4 + 1] << 13) | used[tid * 4 + 1];
        unsigned v2 = (cnt_b[tid * 4 + 2] << 13) | used[tid * 4 + 2];
        unsigned v3 = (cnt_b[tid * 4 + 3] << 13) | used[tid * 4 + 3];
        unsigned tsum = v0 + v1 + v2 + v3;
        unsigned x = tsum;
#pragma unroll
        for (int off = 1; off < 64; off <<= 1) {
            unsigned y = __shfl_up(x, off);
            if (lane >= off) x += y;
        }
        if (lane == 63) wbase[wv + 1] = x;
        __syncthreads();
        if (tid == 0) {
            wbase[0] = 0u;
            for (int w = 1; w <= 16; ++w) wbase[w] += wbase[w - 1];
        }
        __syncthreads();
        unsigned texcl = wbase[wv] + x - tsum;
        pref[tid * 4]     = texcl;
        pref[tid * 4 + 1] = texcl + v0;
        pref[tid * 4 + 2] = texcl + v0 + v1;
        pref[tid * 4 + 3] = texcl + v0 + v1 + v2;
    }
#pragma unroll
    for (int r = 0; r < 4; ++r) cnt_a[tid + r * 1024] = 0u;   // scatter cursors
    __syncthreads();

#pragma unroll
    for (int r = 0; r < 4; ++r) {
        int g = tid + r * 1024;
        unsigned p = pref[g];
        rowptr[b * 4104 + g] = p >> 13;
        unsigned slot = p & 8191u;
        remap[b * CC + g] = slot;
        if (used[g]) inv[b * MAXU + slot] = (unsigned)g;
    }
    if (tid == 0) {
        rowptr[b * 4104 + 4096] = wbase[16] >> 13;
        nused[b] = wbase[16] & 8191u;
    }
    for (int e = tid; e < (int)total; e += 1024) { // adjacency scatter
        unsigned key = lkeys[e];
        unsigned i = key >> 12, j = key & 4095u;
        unsigned pos = (pref[i] >> 13) + atomicAdd(&cnt_a[i], 1u);
        adj[b * 2048 + pos] = j;
    }
}

// One WAVE per used row: ae = s_i*(s_i*E[i] + sum_{i->j} s_j*E[j]) -> ae_c.
// No LDS, no barriers; 4352 blocks give the TLP to hide the edge chains.
__global__ __launch_bounds__(256) void ae_build(const float* __restrict__ E,
                                                const float* __restrict__ s,
                                                const unsigned* __restrict__ rowptr,
                                                const unsigned* __restrict__ adj,
                                                const unsigned* __restrict__ inv,
                                                const unsigned* __restrict__ nused,
                                                float* __restrict__ ae_c) {
    const int b = blockIdx.x / (MAXU / 4);                 // 544 blocks per batch
    const int slot = (blockIdx.x % (MAXU / 4)) * 4 + (threadIdx.x >> 6);
    const int lane = threadIdx.x & 63;
    if ((unsigned)slot >= nused[b]) return;
    unsigned c = inv[b * MAXU + slot];
    float si = s[b * CC + c];
    const float2* Eb = (const float2*)(E + (size_t)b * CC * DD);
    float2 e = Eb[(size_t)c * 64 + lane];
    float2 acc = make_float2(si * e.x, si * e.y);
    unsigned p0 = rowptr[b * 4104 + c], p1 = rowptr[b * 4104 + c + 1];
    for (unsigned p = p0; p < p1; ++p) {
        unsigned j = adj[b * 2048 + p];
        float sj = s[b * CC + j];
        float2 ej = Eb[(size_t)j * 64 + lane];
        acc.x += sj * ej.x;
        acc.y += sj * ej.y;
    }
    ((float2*)ae_c)[((size_t)b * MAXU + slot) * 64 + lane] =
        make_float2(si * acc.x, si * acc.y);
}

// Compact dense GEMM: eg_c = relu(ae_c @ W^T + bias). 32 rows/block.
// R8 read Wt from global per k-iter: 544 blocks x 1MB streamed from L2
// (Wt=64KB > 32KB L1) ~= 544MB ~= 16us L2-bound. Fix: K-split LDS staging
// of Ws (32KB) + As (16.4KB) = 49.5KB -> 3 blocks/CU, 12 waves/CU; W L2
// traffic drops to 34MB total.
__global__ __launch_bounds__(256) void gemm_eg(const float* __restrict__ ae_c,
                                               const float* __restrict__ Wt,
                                               const float* __restrict__ bg,
                                               const unsigned* __restrict__ nused,
                                               float* __restrict__ eg_c) {
    __shared__ float As[32][131];
    __shared__ float Ws[64][128];
    const int b = blockIdx.x / (MAXU / 32);                // 68 blocks per batch
    const int s0 = (blockIdx.x % (MAXU / 32)) * 32;
    const unsigned nu = nused[b];
    if ((unsigned)s0 >= nu) return;
    const int tid = threadIdx.x;

    // stage 32 ae rows (poison rows beyond nu are harmless f32 garbage)
    for (int idx = tid; idx < 1024; idx += 256) {
        int row = idx >> 5, f4 = idx & 31;
        float4 v = ((const float4*)ae_c)[((size_t)b * MAXU + s0 + row) * 32 + f4];
        As[row][f4 * 4]     = v.x;
        As[row][f4 * 4 + 1] = v.y;
        As[row][f4 * 4 + 2] = v.z;
        As[row][f4 * 4 + 3] = v.w;
    }

    const int tr = tid >> 4, tc = tid & 15;
    float bgv[8];
#pragma unroll
    for (int c = 0; c < 8; ++c) bgv[c] = bg[tc * 8 + c];
    float acc[2][8];
#pragma unroll
    for (int r = 0; r < 2; ++r)
#pragma unroll
        for (int c = 0; c < 8; ++c) acc[r][c] = 0.f;

    for (int kk = 0; kk < 128; kk += 64) {
        __syncthreads();                           // As ready / Ws reusable
        for (int idx = tid; idx < 64 * 128; idx += 256) {   // stage W half
            int kl = idx >> 7, n = idx & 127;
            Ws[kl][n] = Wt[(kk + kl) * 128 + n];   // coalesced
        }
        __syncthreads();
#pragma unroll 4
        for (int kl = 0; kl < 64; ++kl) {
            float a0 = As[tr * 2][kk + kl];        // 16 distinct banks
            float a1 = As[tr * 2 + 1][kk + kl];
            const float4* wp = (const float4*)&Ws[kl][tc * 8];
            float4 w0 = wp[0], w1 = wp[1];
            float wvv[8] = {w0.x, w0.y, w0.z, w0.w, w1.x, w1.y, w1.z, w1.w};
#pragma unroll
            for (int c = 0; c < 8; ++c) {
                acc[0][c] = fmaf(a0, wvv[c], acc[0][c]);
                acc[1][c] = fmaf(a1, wvv[c], acc[1][c]);
            }
        }
    }

#pragma unroll
    for (int r = 0; r < 2; ++r) {
        int row = tr * 2 + r;
        float4 o0, o1;
        o0.x = fmaxf(acc[r][0] + bgv[0], 0.f);
        o0.y = fmaxf(acc[r][1] + bgv[1], 0.f);
        o0.z = fmaxf(acc[r][2] + bgv[2], 0.f);
        o0.w = fmaxf(acc[r][3] + bgv[3], 0.f);
        o1.x = fmaxf(acc[r][4] + bgv[4], 0.f);
        o1.y = fmaxf(acc[r][5] + bgv[5], 0.f);
        o1.z = fmaxf(acc[r][6] + bgv[6], 0.f);
        o1.w = fmaxf(acc[r][7] + bgv[7], 0.f);
        float* outp = eg_c + ((size_t)b * MAXU + s0 + row) * 128 + tc * 8;
        ((float4*)outp)[0] = o0;
        ((float4*)outp)[1] = o1;
    }
}

// One wave per output row: out[row] = [eg_c[remap[cand]] | E[cand]] + te[s].
__global__ __launch_bounds__(256) void scatter_out(const int* __restrict__ hist,
                                                   const int* __restrict__ cur,
                                                   const unsigned* __restrict__ remap,
                                                   const float4* __restrict__ Egc4,
                                                   const float4* __restrict__ E4,
                                                   const float4* __restrict__ te4,
                                                   float4* __restrict__ out4) {
    int g = blockIdx.x * 256 + threadIdx.x;
    int row = g >> 6, lane = g & 63;
    int b, spos, cand;
    if (row < BB * HH * SS) {
        spos = row & 63;
        b = row >> 11;
        cand = hist[row];
    } else {
        int rc = row - BB * HH * SS;
        spos = rc & 63;
        b = rc >> 6;
        cand = cur[rc];
    }
    float4 v;
    if (lane < 32) {
        unsigned slot = remap[b * CC + cand];
        v = Egc4[((size_t)b * MAXU + slot) * 32 + lane];
    } else {
        v = E4[(size_t)(b * CC + cand) * 32 + (lane - 32)];
    }
    float4 t = te4[spos * 64 + lane];
    out4[(size_t)row * 64 + lane] = make_float4(v.x + t.x, v.y + t.y, v.z + t.z, v.w + t.w);
}

extern "C" void kernel_launch(void* const* d_in, const int* in_sizes, int n_in,
                              void* d_out, int out_size, void* d_ws, size_t ws_size,
                              hipStream_t stream) {
    const int*   hist = (const int*)d_in[1];
    const int*   cur  = (const int*)d_in[2];
    const float* E    = (const float*)d_in[3];
    const float* W    = (const float*)d_in[4];
    const float* bg   = (const float*)d_in[5];
    float* out = (float*)d_out;

    unsigned* ws_u   = (unsigned*)d_ws;
    unsigned* rowptr = ws_u;                         // 32832
    unsigned* adj    = rowptr + 32832;               // 16384
    float*    sarr   = (float*)(adj + 16384);        // 32768
    float*    te     = sarr + 32768;                 // 16384
    unsigned* inv    = (unsigned*)(te + 16384);      // 17408
    unsigned* remap  = inv + 17408;                  // 32768
    unsigned* nused  = remap + 32768;                // 64
    float*    Wt     = (float*)(nused + 64);         // 16384
    float*    ae_c   = Wt + 16384;                   // 2228224
    float*    eg_c   = ae_c + 2228224;               // 2228224

    build_graph<<<BB + 32, 1024, 0, stream>>>(hist, cur, W, rowptr, adj, sarr,
                                              inv, remap, nused, te, Wt);
    ae_build<<<BB * (MAXU / 4), 256, 0, stream>>>(E, sarr, rowptr, adj, inv,
                                                  nused, ae_c);
    gemm_eg<<<BB * (MAXU / 32), 256, 0, stream>>>(ae_c, Wt, bg, nused, eg_c);
    scatter_out<<<(BB * HH * SS + BB * SS) / 4, 256, 0, stream>>>(
        hist, cur, remap, (const float4*)eg_c, (const float4*)E,
        (const float4*)te, (float4*)out);
}